// Round 1
// baseline (598.766 us; speedup 1.0000x reference)
//
#include <hip/hip_runtime.h>
#include <stdint.h>

#define N_NODES 50000
#define N_PAD   50048                // padded to 128-row multiple for gemm tiles
#define NNZ     800000
#define SUP     3
#define D_IN    512
#define D_OUT   256
#define TOT_E   (SUP * NNZ)          // 2,400,000
#define CAPR    128                  // per-row CSR capacity (mean 48, P(>=128)~1e-20/row)
#define NB_WPREP 1536                // 393216 / 256
#define NB_XPREP 12500               // 3,200,000 / 256
#define NB_GEMM  2346                // 391 m-tiles * 6 (n-tile x support)
#define NB_SCAT  9375                // 2,400,000 / 256

typedef __attribute__((ext_vector_type(8))) short bf16x8;
typedef __attribute__((ext_vector_type(4))) float f32x4;
typedef __attribute__((address_space(3))) unsigned int lds_u32_t;
typedef const __attribute__((address_space(1))) unsigned int glb_u32_t;

static __device__ __forceinline__ unsigned short f2bf(float f) {
    unsigned int u = __float_as_uint(f);
    unsigned int r = (u + 0x7fffu + ((u >> 16) & 1u)) >> 16;
    return (unsigned short)r;
}
static __device__ __forceinline__ unsigned int pack_bf2(float lo, float hi) {
    unsigned int a = __float_as_uint(lo) + 0x8000u;
    unsigned int b = __float_as_uint(hi) + 0x8000u;
    return (a >> 16) | (b & 0xffff0000u);
}
static __device__ __forceinline__ float bf2f(unsigned short h) {
    return __uint_as_float(((unsigned int)h) << 16);
}
static __device__ __forceinline__ int2 ldnt_int2(const int2* p) {
    long long v = __builtin_nontemporal_load((const long long*)p);
    int2 r;
    r.x = (int)(v & 0xffffffffLL);
    r.y = (int)(v >> 32);
    return r;
}

// ============ prep: pure streaming conversions, zero LDS =========================
// [0, NB_XPREP): x fp32 -> bf16, 8 elems/thread
// [NB_XPREP, NB_XPREP+NB_WPREP): W[s][k][n] -> Wt[s][n][k] bf16
__global__ __launch_bounds__(256) void prep_kernel(const float* __restrict__ x,
                                                   unsigned int* __restrict__ xb,
                                                   const float* __restrict__ W,
                                                   unsigned short* __restrict__ Wt) {
    const int blk = blockIdx.x;
    const int tid = threadIdx.x;
    if (blk < NB_XPREP) {
        int idx = blk * 256 + tid;                 // < 3,200,000 exactly
        const f32x4* src = (const f32x4*)(x) + idx * 2;
        f32x4 f0 = __builtin_nontemporal_load(src);
        f32x4 f1 = __builtin_nontemporal_load(src + 1);
        uint4 o;
        o.x = pack_bf2(f0.x, f0.y);
        o.y = pack_bf2(f0.z, f0.w);
        o.z = pack_bf2(f1.x, f1.y);
        o.w = pack_bf2(f1.z, f1.w);
        *((uint4*)xb + idx) = o;
    } else {
        int idx = (blk - NB_XPREP) * 256 + tid;    // < 393216 exactly
        int n = idx & (D_OUT - 1);
        int k = (idx >> 8) & (D_IN - 1);
        int s = idx >> 17;
        Wt[((size_t)s * D_OUT + n) * D_IN + k] = f2bf(W[idx]);
    }
}

// ============ fused: [0,NB_GEMM) m97-style GEMM | [NB_GEMM,..) edge scatter ======
// GEMM: pre[s] = xb @ Wt[s]^T (bf16 MFMA, 128x128 tile, 32KB LDS -> 3 blocks/CU)
// Scatter: one-pass padded-CSR build: cv[r*128 + atomicAdd(cnt[r])] = {s*N+c, v*cw[s]}
__global__ __launch_bounds__(256) void gemmscat_kernel(const unsigned short* __restrict__ xb,
                                                       const unsigned short* __restrict__ Wt,
                                                       unsigned short* __restrict__ pre,
                                                       const int* __restrict__ rows,
                                                       const int* __restrict__ cols,
                                                       const float* __restrict__ vals,
                                                       const float* __restrict__ cw,
                                                       int* __restrict__ cnt,
                                                       int2* __restrict__ cv) {
    __shared__ unsigned short lds_a[128 * 64];    // 16384 B
    __shared__ unsigned short lds_b[128 * 64];    // 16384 B
    const int blk = blockIdx.x;
    const int tid = threadIdx.x;

    if (blk >= NB_GEMM) {
        // ---- scatter: one edge per thread ----
        int e = (blk - NB_GEMM) * 256 + tid;       // < 2,400,000 exactly
        int s = (e >= 2 * NNZ) ? 2 : ((e >= NNZ) ? 1 : 0);
        int r = __builtin_nontemporal_load(&rows[e]);
        int c = __builtin_nontemporal_load(&cols[e]);
        float v = __builtin_nontemporal_load(&vals[e]);
        float w = v * cw[s];
        int p = atomicAdd(&cnt[r], 1);
        if (p < CAPR) {
            long long packed = ((long long)__float_as_int(w) << 32) |
                               (unsigned int)(s * N_NODES + c);
            __builtin_nontemporal_store(packed, (long long*)&cv[(size_t)r * CAPR + p]);
        }
        return;
    }

    // ---- GEMM: XCD-chunked bijective swizzle so the 6 sharers of an m-tile
    //      land on the same XCD (xb tile stays in one L2) ----
    constexpr int SWQ = NB_GEMM / 8;   // 293
    constexpr int SWR = NB_GEMM % 8;   // 2
    const int xcd = blk & 7, pos = blk >> 3;
    const int my = (xcd < SWR ? xcd * (SWQ + 1)
                              : SWR * (SWQ + 1) + (xcd - SWR) * SWQ) + pos;
    const int mt  = my / 6;
    const int rem = my % 6;                // sharers of m-tile adjacent
    const int m0 = mt * 128;
    const int n0 = (rem & 1) * 128;
    const int s  = rem >> 1;
    const unsigned short* wt = Wt + (size_t)s * D_OUT * D_IN;
    const int wave = tid >> 6;
    const int lane = tid & 63;
    const int quad = lane >> 4;
    const int lo   = lane & 15;
    const int wm = (wave & 1) * 64;
    const int wn = (wave >> 1) * 64;

    f32x4 acc[4][4] = {};

    for (int kb = 0; kb < D_IN; kb += 64) {
        __syncthreads();
        #pragma unroll
        for (int c = 0; c < 4; ++c) {
            int idx = c * 256 + tid;
            int row = idx >> 3;
            int kp  = idx & 7;
            const unsigned short* ga = xb + (size_t)(m0 + row) * D_IN + kb + kp * 8;
            __builtin_amdgcn_global_load_lds((glb_u32_t*)ga,
                                             (lds_u32_t*)&lds_a[idx * 8], 16, 0, 0);
            const unsigned short* gb = wt + (size_t)(n0 + row) * D_IN + kb + kp * 8;
            __builtin_amdgcn_global_load_lds((glb_u32_t*)gb,
                                             (lds_u32_t*)&lds_b[idx * 8], 16, 0, 0);
        }
        __syncthreads();

        #pragma unroll
        for (int t = 0; t < 2; ++t) {
            bf16x8 af[4], bfr[4];
            #pragma unroll
            for (int i = 0; i < 4; ++i)
                af[i] = *(const bf16x8*)&lds_a[(wm + 16 * i + lo) * 64 + t * 32 + quad * 8];
            #pragma unroll
            for (int j = 0; j < 4; ++j)
                bfr[j] = *(const bf16x8*)&lds_b[(wn + 16 * j + lo) * 64 + t * 32 + quad * 8];
            #pragma unroll
            for (int i = 0; i < 4; ++i)
                #pragma unroll
                for (int j = 0; j < 4; ++j)
                    acc[i][j] = __builtin_amdgcn_mfma_f32_16x16x32_bf16(af[i], bfr[j], acc[i][j], 0, 0, 0);
        }
    }

    // epilogue: C layout col=lane&15, row=quad*4+reg
    #pragma unroll
    for (int i = 0; i < 4; ++i) {
        #pragma unroll
        for (int j = 0; j < 4; ++j) {
            int gn = n0 + wn + 16 * j + lo;
            #pragma unroll
            for (int r = 0; r < 4; ++r) {
                int gm2 = m0 + wm + 16 * i + quad * 4 + r;
                if (gm2 < N_NODES)
                    pre[((size_t)s * N_NODES + gm2) * D_OUT + gn] = f2bf(acc[i][j][r]);
            }
        }
    }
}

// ---------------- SpMM + ReLU: half-wave 16B gathers, pipelined cv loads ----------
// lanes 0-31 process even edges, 32-63 odd edges; each half-wave reads a full
// 512B pre row at 16B/lane.  cv row segment [row*128, +cnt) aliases out row
// [row*256 floats): all reads retire before the same wave's stores (safe).
__global__ __launch_bounds__(256) void spmm_kernel(const unsigned short* __restrict__ pre,
                                                   const int* __restrict__ cnt,
                                                   const int2* __restrict__ cv,
                                                   float* __restrict__ out) {
    const int row  = blockIdx.x * 4 + (threadIdx.x >> 6);
    const int lane = threadIdx.x & 63;
    const int half = lane >> 5;
    const int l32  = lane & 31;
    const long start = (long)row * CAPR;
    const int  n   = min(cnt[row], CAPR);
    const long end = start + n;

    float a[8] = {};
    long j = start;

    if (j + 8 <= end) {
        int2 e0 = ldnt_int2(&cv[j + 0 + half]);
        int2 e1 = ldnt_int2(&cv[j + 2 + half]);
        int2 e2 = ldnt_int2(&cv[j + 4 + half]);
        int2 e3 = ldnt_int2(&cv[j + 6 + half]);
        for (;;) {
            bf16x8 p0 = *(const bf16x8*)(pre + (size_t)(unsigned)e0.x * D_OUT + l32 * 8);
            bf16x8 p1 = *(const bf16x8*)(pre + (size_t)(unsigned)e1.x * D_OUT + l32 * 8);
            bf16x8 p2 = *(const bf16x8*)(pre + (size_t)(unsigned)e2.x * D_OUT + l32 * 8);
            bf16x8 p3 = *(const bf16x8*)(pre + (size_t)(unsigned)e3.x * D_OUT + l32 * 8);
            long jn = j + 8;
            bool more = (jn + 8 <= end);
            int2 f0, f1, f2, f3;
            if (more) {                       // prefetch next 8 edges under the FMAs
                f0 = ldnt_int2(&cv[jn + 0 + half]);
                f1 = ldnt_int2(&cv[jn + 2 + half]);
                f2 = ldnt_int2(&cv[jn + 4 + half]);
                f3 = ldnt_int2(&cv[jn + 6 + half]);
            }
            float w0 = __int_as_float(e0.y);
            float w1 = __int_as_float(e1.y);
            float w2 = __int_as_float(e2.y);
            float w3 = __int_as_float(e3.y);
            #pragma unroll
            for (int k = 0; k < 8; ++k) {
                a[k] += w0 * bf2f((unsigned short)p0[k]);
                a[k] += w1 * bf2f((unsigned short)p1[k]);
                a[k] += w2 * bf2f((unsigned short)p2[k]);
                a[k] += w3 * bf2f((unsigned short)p3[k]);
            }
            j = jn;
            if (!more) break;
            e0 = f0; e1 = f1; e2 = f2; e3 = f3;
        }
    }
    for (; j < end; j += 2) {                 // tail: 2 edges per step
        long idx = j + half;
        int2 e = (idx < end) ? ldnt_int2(&cv[idx]) : make_int2(0, 0);
        float w = __int_as_float(e.y);
        bf16x8 p = *(const bf16x8*)(pre + (size_t)(unsigned)e.x * D_OUT + l32 * 8);
        #pragma unroll
        for (int k = 0; k < 8; ++k) a[k] += w * bf2f((unsigned short)p[k]);
    }

    // combine even/odd halves: lane i <-> lane i^32 hold the same 8 columns
    #pragma unroll
    for (int k = 0; k < 8; ++k) a[k] += __shfl_xor(a[k], 32);

    if (half == 0) {
        f32x4 o0, o1;
        o0.x = fmaxf(a[0], 0.f); o0.y = fmaxf(a[1], 0.f);
        o0.z = fmaxf(a[2], 0.f); o0.w = fmaxf(a[3], 0.f);
        o1.x = fmaxf(a[4], 0.f); o1.y = fmaxf(a[5], 0.f);
        o1.z = fmaxf(a[6], 0.f); o1.w = fmaxf(a[7], 0.f);
        float* dst = out + (size_t)row * D_OUT + l32 * 8;
        __builtin_nontemporal_store(o0, (f32x4*)dst);
        __builtin_nontemporal_store(o1, (f32x4*)(dst + 4));
    }
}

extern "C" void kernel_launch(void* const* d_in, const int* in_sizes, int n_in,
                              void* d_out, int out_size, void* d_ws, size_t ws_size,
                              hipStream_t stream) {
    const float* x    = (const float*)d_in[0];
    const float* W    = (const float*)d_in[1];
    const int*   rows = (const int*)d_in[2];
    const int*   cols = (const int*)d_in[3];
    const float* vals = (const float*)d_in[4];
    const float* cw   = (const float*)d_in[5];
    float* out = (float*)d_out;

    char* ws = (char*)d_ws;
    size_t off = 0;
    auto alloc = [&](size_t bytes) -> void* {
        void* p = ws + off;
        off += (bytes + 255) & ~(size_t)255;
        return p;
    };
    unsigned short* pre  = (unsigned short*)alloc((size_t)SUP * N_NODES * D_OUT * 2); // 76.8 MB
    unsigned short* xb   = (unsigned short*)alloc((size_t)N_PAD * D_IN * 2);          // 51.25 MB
    unsigned short* Wt   = (unsigned short*)alloc((size_t)SUP * D_OUT * D_IN * 2);    // 0.8 MB
    int* cnt             = (int*)alloc((size_t)N_NODES * 4);                          // 0.2 MB
    // cv: padded per-row CSR, 50000 rows x 128 slots x 8B = 51,200,000 B = d_out
    // exactly.  Written by gemmscat's scatter blocks, consumed (then overwritten
    // row-by-row, same wave) by spmm.
    int2* cv             = (int2*)d_out;

    hipMemsetAsync(cnt, 0, (size_t)N_NODES * 4, stream);

    prep_kernel<<<NB_XPREP + NB_WPREP, 256, 0, stream>>>(x, (unsigned int*)xb, W, Wt);
    gemmscat_kernel<<<NB_GEMM + NB_SCAT, 256, 0, stream>>>(
        xb, Wt, pre, rows, cols, vals, cw, cnt, cv);
    spmm_kernel<<<N_NODES / 4, 256, 0, stream>>>(pre, cnt, cv, out);
}

// Round 2
// 477.836 us; speedup vs baseline: 1.2531x; 1.2531x over previous
//
#include <hip/hip_runtime.h>
#include <stdint.h>

#define N_NODES 50000
#define N_PAD   50048                // padded to 128-row multiple for gemm tiles
#define NNZ     800000
#define SUP     3
#define D_IN    512
#define D_OUT   256
#define TOT_E   (SUP * NNZ)          // 2,400,000
#define NBUCK   391                  // ceil(50000/128) : 128-row buckets
#define CAP     6976                 // per-bucket capacity (mean 6144, +10.6 sigma)
#define CHUNK   6144                 // edges per bucket block
#define NB_WPREP 1536                // 393216 / 256
#define NB_XPREP 12500               // 3,200,000 / 256
#define NB_GEMM  2346                // 391 m-tiles * 6 (n-tile x support)

typedef __attribute__((ext_vector_type(8))) short bf16x8;
typedef __attribute__((ext_vector_type(4))) float f32x4;
typedef __attribute__((address_space(3))) unsigned int lds_u32_t;
typedef const __attribute__((address_space(1))) unsigned int glb_u32_t;

static __device__ __forceinline__ unsigned short f2bf(float f) {
    unsigned int u = __float_as_uint(f);
    unsigned int r = (u + 0x7fffu + ((u >> 16) & 1u)) >> 16;
    return (unsigned short)r;
}
static __device__ __forceinline__ unsigned int pack_bf2(float lo, float hi) {
    unsigned int a = __float_as_uint(lo) + 0x8000u;
    unsigned int b = __float_as_uint(hi) + 0x8000u;
    return (a >> 16) | (b & 0xffff0000u);
}
static __device__ __forceinline__ float bf2f(unsigned short h) {
    return __uint_as_float(((unsigned int)h) << 16);
}

// ============ prep: pure streaming conversions, zero LDS (8 blk/CU) ==============
// [0, NB_XPREP): x fp32 -> bf16, 8 elems/thread
// [NB_XPREP, NB_XPREP+NB_WPREP): W[s][k][n] -> Wt[s][n][k] bf16
__global__ __launch_bounds__(256) void prep_kernel(const float* __restrict__ x,
                                                   unsigned int* __restrict__ xb,
                                                   const float* __restrict__ W,
                                                   unsigned short* __restrict__ Wt) {
    const int blk = blockIdx.x;
    const int tid = threadIdx.x;
    if (blk < NB_XPREP) {
        int idx = blk * 256 + tid;                 // < 3,200,000 exactly
        const f32x4* src = (const f32x4*)(x) + idx * 2;
        f32x4 f0 = __builtin_nontemporal_load(src);
        f32x4 f1 = __builtin_nontemporal_load(src + 1);
        uint4 o;
        o.x = pack_bf2(f0.x, f0.y);
        o.y = pack_bf2(f0.z, f0.w);
        o.z = pack_bf2(f1.x, f1.y);
        o.w = pack_bf2(f1.z, f1.w);
        *((uint4*)xb + idx) = o;
    } else {
        int idx = (blk - NB_XPREP) * 256 + tid;    // < 393216 exactly
        int n = idx & (D_OUT - 1);
        int k = (idx >> 8) & (D_IN - 1);
        int s = idx >> 17;
        Wt[((size_t)s * D_OUT + n) * D_IN + k] = f2bf(W[idx]);
    }
}

// ============ bucket: edges by row>>7, coalesced run writes (391 blocks) =========
__global__ __launch_bounds__(256) void bucket_kernel(const int* __restrict__ rows,
                                                     const int* __restrict__ cols,
                                                     const float* __restrict__ vals,
                                                     const float* __restrict__ cw,
                                                     int* __restrict__ bucket_cursor,
                                                     int2* __restrict__ buck) {
    __shared__ double smem8[8590];           // 68720 B
    char* smem = (char*)smem8;
    const int blk = blockIdx.x;
    const int tid = threadIdx.x;

    int2* stage = (int2*)smem;                               // 49152 B
    unsigned short* bucket_of = (unsigned short*)(smem + 49152); // 12288 B
    int* hist   = (int*)(smem + 61440);                      // [391]
    int* sc     = hist + NBUCK;                              // [256]
    int* sstart = sc + 256;                                  // [391]
    int* lcur   = sstart + NBUCK;                            // [391]
    int* gbase  = lcur + NBUCK;                              // [391]

    const int base_n = blk * CHUNK;
    const int count = min(CHUNK, TOT_E - base_n);
    float cw0 = cw[0], cw1 = cw[1], cw2 = cw[2];

    for (int i = tid; i < NBUCK; i += 256) hist[i] = 0;
    __syncthreads();
    for (int i = tid; i < count; i += 256)
        atomicAdd(&hist[rows[base_n + i] >> 7], 1);
    __syncthreads();
    int b0 = 2 * tid, b1 = b0 + 1;
    int h0 = (b0 < NBUCK) ? hist[b0] : 0;
    int h1 = (b1 < NBUCK) ? hist[b1] : 0;
    sc[tid] = h0 + h1;
    __syncthreads();
    for (int off = 1; off < 256; off <<= 1) {
        int t = (tid >= off) ? sc[tid - off] : 0;
        __syncthreads();
        sc[tid] += t;
        __syncthreads();
    }
    int excl = sc[tid] - (h0 + h1);
    if (b0 < NBUCK) { sstart[b0] = excl;      lcur[b0] = excl; }
    if (b1 < NBUCK) { sstart[b1] = excl + h0; lcur[b1] = excl + h0; }
    for (int i = tid; i < NBUCK; i += 256)
        gbase[i] = atomicAdd(&bucket_cursor[i], hist[i]);
    __syncthreads();
    for (int i = tid; i < count; i += 256) {
        int n = base_n + i;
        int r = rows[n];
        int c = cols[n];
        float v = vals[n];
        int s = n / NNZ;
        float w = v * (s == 0 ? cw0 : (s == 1 ? cw1 : cw2));
        int b = r >> 7;
        int p = atomicAdd(&lcur[b], 1);
        stage[p] = make_int2(((r & 127) << 18) | (s * N_NODES + c), __float_as_int(w));
        bucket_of[p] = (unsigned short)b;
    }
    __syncthreads();
    for (int i = tid; i < count; i += 256) {
        int b = bucket_of[i];
        int local_off = i - sstart[b];
        buck[(size_t)b * CAP + gbase[b] + local_off] = stage[i];
    }
}

// ============ sort: one 128-row bucket via LDS, emit CSR + base/cnt ==============
__global__ __launch_bounds__(256) void sort_kernel(const int2* __restrict__ buck,
                                                   const int* __restrict__ bucket_cursor,
                                                   int2* __restrict__ cv,
                                                   int* __restrict__ base,
                                                   int* __restrict__ cnt) {
    __shared__ double smem8[7232];           // 57856 B
    char* smem = (char*)smem8;
    const int tid = threadIdx.x;

    int2* stage = (int2*)smem;                   // 55808 B
    int* hist   = (int*)(smem + 55808);          // [128]
    int* sc     = hist + 128;
    int* sstart = sc + 128;
    int* cur    = sstart + 128;

    const int b = blockIdx.x;
    const int sz = bucket_cursor[b];
    const int2* src = buck + (size_t)b * CAP;

    if (tid < 128) hist[tid] = 0;
    __syncthreads();
    for (int i = tid; i < sz; i += 256)
        atomicAdd(&hist[((unsigned)src[i].x) >> 18], 1);
    __syncthreads();
    if (tid < 128) sc[tid] = hist[tid];
    __syncthreads();
    for (int off = 1; off < 128; off <<= 1) {
        int t = (tid >= off && tid < 128) ? sc[tid - off] : 0;
        __syncthreads();
        if (tid < 128) sc[tid] += t;
        __syncthreads();
    }
    if (tid < 128) {
        int st = sc[tid] - hist[tid];
        sstart[tid] = st;
        cur[tid] = st;
    }
    __syncthreads();
    for (int i = tid; i < sz; i += 256) {
        int2 e = src[i];
        int rl = ((unsigned)e.x) >> 18;
        int p = atomicAdd(&cur[rl], 1);
        stage[p] = make_int2(e.x & 0x3FFFF, e.y);
    }
    __syncthreads();
    size_t gb = (size_t)b * CAP;
    for (int i = tid; i < sz; i += 256) cv[gb + i] = stage[i];
    int r = b * 128 + tid;
    if (tid < 128 && r < N_NODES) {
        base[r] = (int)gb + sstart[tid];
        cnt[r]  = hist[tid];
    }
}

// ============ m97-style bf16 MFMA GEMM: pre[s] = xb @ Wt[s]^T (32KB LDS) =========
__global__ __launch_bounds__(256) void gemm_kernel(const unsigned short* __restrict__ xb,
                                                   const unsigned short* __restrict__ Wt,
                                                   unsigned short* __restrict__ pre) {
    __shared__ unsigned short lds_a[128 * 64];    // 16384 B
    __shared__ unsigned short lds_b[128 * 64];    // 16384 B
    const int blk = blockIdx.x;
    const int tid = threadIdx.x;

    // XCD-chunked bijective swizzle: the 6 sharers of an m-tile land on one XCD
    constexpr int SWQ = NB_GEMM / 8;   // 293
    constexpr int SWR = NB_GEMM % 8;   // 2
    const int xcd = blk & 7, pos = blk >> 3;
    const int my = (xcd < SWR ? xcd * (SWQ + 1)
                              : SWR * (SWQ + 1) + (xcd - SWR) * SWQ) + pos;
    const int mt  = my / 6;
    const int rem = my % 6;                // sharers of m-tile adjacent
    const int m0 = mt * 128;
    const int n0 = (rem & 1) * 128;
    const int s  = rem >> 1;
    const unsigned short* wt = Wt + (size_t)s * D_OUT * D_IN;
    const int wave = tid >> 6;
    const int lane = tid & 63;
    const int quad = lane >> 4;
    const int lo   = lane & 15;
    const int wm = (wave & 1) * 64;
    const int wn = (wave >> 1) * 64;

    f32x4 acc[4][4] = {};

    for (int kb = 0; kb < D_IN; kb += 64) {
        __syncthreads();
        #pragma unroll
        for (int c = 0; c < 4; ++c) {
            int idx = c * 256 + tid;
            int row = idx >> 3;
            int kp  = idx & 7;
            const unsigned short* ga = xb + (size_t)(m0 + row) * D_IN + kb + kp * 8;
            __builtin_amdgcn_global_load_lds((glb_u32_t*)ga,
                                             (lds_u32_t*)&lds_a[idx * 8], 16, 0, 0);
            const unsigned short* gb = wt + (size_t)(n0 + row) * D_IN + kb + kp * 8;
            __builtin_amdgcn_global_load_lds((glb_u32_t*)gb,
                                             (lds_u32_t*)&lds_b[idx * 8], 16, 0, 0);
        }
        __syncthreads();

        #pragma unroll
        for (int t = 0; t < 2; ++t) {
            bf16x8 af[4], bfr[4];
            #pragma unroll
            for (int i = 0; i < 4; ++i)
                af[i] = *(const bf16x8*)&lds_a[(wm + 16 * i + lo) * 64 + t * 32 + quad * 8];
            #pragma unroll
            for (int j = 0; j < 4; ++j)
                bfr[j] = *(const bf16x8*)&lds_b[(wn + 16 * j + lo) * 64 + t * 32 + quad * 8];
            #pragma unroll
            for (int i = 0; i < 4; ++i)
                #pragma unroll
                for (int j = 0; j < 4; ++j)
                    acc[i][j] = __builtin_amdgcn_mfma_f32_16x16x32_bf16(af[i], bfr[j], acc[i][j], 0, 0, 0);
        }
    }

    // epilogue: C layout col=lane&15, row=quad*4+reg
    #pragma unroll
    for (int i = 0; i < 4; ++i) {
        #pragma unroll
        for (int j = 0; j < 4; ++j) {
            int gn = n0 + wn + 16 * j + lo;
            #pragma unroll
            for (int r = 0; r < 4; ++r) {
                int gm2 = m0 + wm + 16 * i + quad * 4 + r;
                if (gm2 < N_NODES)
                    pre[((size_t)s * N_NODES + gm2) * D_OUT + gn] = f2bf(acc[i][j][r]);
            }
        }
    }
}

// ---------------- fused SpMM (combined CSR) + ReLU, unroll x8 ----------------------
__global__ __launch_bounds__(256) void spmm_kernel(const unsigned short* __restrict__ pre,
                                                   const int* __restrict__ base,
                                                   const int* __restrict__ cnt,
                                                   const int2* __restrict__ cv,
                                                   float* __restrict__ out) {
    int row  = blockIdx.x * 4 + (threadIdx.x >> 6);
    int lane = threadIdx.x & 63;
    int start = base[row];
    int end   = start + cnt[row];
    float a0 = 0.f, a1 = 0.f, a2 = 0.f, a3 = 0.f;
    int j = start;
    for (; j + 8 <= end; j += 8) {
        int2 e[8];
        #pragma unroll
        for (int q = 0; q < 8; ++q) e[q] = cv[j + q];
        ushort4 p[8];
        #pragma unroll
        for (int q = 0; q < 8; ++q)
            p[q] = *(const ushort4*)(pre + (size_t)e[q].x * D_OUT + lane * 4);
        #pragma unroll
        for (int q = 0; q < 8; ++q) {
            float w = __int_as_float(e[q].y);
            a0 += w * bf2f(p[q].x);
            a1 += w * bf2f(p[q].y);
            a2 += w * bf2f(p[q].z);
            a3 += w * bf2f(p[q].w);
        }
    }
    for (; j + 4 <= end; j += 4) {
        int2 e[4];
        #pragma unroll
        for (int q = 0; q < 4; ++q) e[q] = cv[j + q];
        ushort4 p[4];
        #pragma unroll
        for (int q = 0; q < 4; ++q)
            p[q] = *(const ushort4*)(pre + (size_t)e[q].x * D_OUT + lane * 4);
        #pragma unroll
        for (int q = 0; q < 4; ++q) {
            float w = __int_as_float(e[q].y);
            a0 += w * bf2f(p[q].x);
            a1 += w * bf2f(p[q].y);
            a2 += w * bf2f(p[q].z);
            a3 += w * bf2f(p[q].w);
        }
    }
    for (; j < end; ++j) {
        int2 e = cv[j];
        float w = __int_as_float(e.y);
        ushort4 p = *(const ushort4*)(pre + (size_t)e.x * D_OUT + lane * 4);
        a0 += w * bf2f(p.x);
        a1 += w * bf2f(p.y);
        a2 += w * bf2f(p.z);
        a3 += w * bf2f(p.w);
    }
    float4 o = make_float4(fmaxf(a0, 0.f), fmaxf(a1, 0.f), fmaxf(a2, 0.f), fmaxf(a3, 0.f));
    *(float4*)(out + (size_t)row * D_OUT + lane * 4) = o;
}

extern "C" void kernel_launch(void* const* d_in, const int* in_sizes, int n_in,
                              void* d_out, int out_size, void* d_ws, size_t ws_size,
                              hipStream_t stream) {
    const float* x    = (const float*)d_in[0];
    const float* W    = (const float*)d_in[1];
    const int*   rows = (const int*)d_in[2];
    const int*   cols = (const int*)d_in[3];
    const float* vals = (const float*)d_in[4];
    const float* cw   = (const float*)d_in[5];
    float* out = (float*)d_out;

    char* ws = (char*)d_ws;
    size_t off = 0;
    auto alloc = [&](size_t bytes) -> void* {
        void* p = ws + off;
        off += (bytes + 255) & ~(size_t)255;
        return p;
    };
    unsigned short* pre  = (unsigned short*)alloc((size_t)SUP * N_NODES * D_OUT * 2); // 76.8 MB
    unsigned short* xb   = (unsigned short*)alloc((size_t)N_PAD * D_IN * 2);          // 51.25 MB
    unsigned short* Wt   = (unsigned short*)alloc((size_t)SUP * D_OUT * D_IN * 2);    // 0.8 MB
    int* base            = (int*)alloc((size_t)N_NODES * 4);
    int* cnt             = (int*)alloc((size_t)N_NODES * 4);
    int* bucket_cursor   = (int*)alloc((size_t)NBUCK * 4);
    int2* cv             = (int2*)alloc((size_t)NBUCK * CAP * 8);                     // 21.8 MB
    // buck lives in d_out (51.2 MB >= 21.8 MB): written by bucket, read by sort,
    // dead before spmm overwrites out.
    int2* buck           = (int2*)d_out;

    hipMemsetAsync(bucket_cursor, 0, (size_t)NBUCK * 4, stream);

    bucket_kernel<<<NBUCK, 256, 0, stream>>>(rows, cols, vals, cw, bucket_cursor, buck);
    prep_kernel<<<NB_XPREP + NB_WPREP, 256, 0, stream>>>(x, (unsigned int*)xb, W, Wt);
    sort_kernel<<<NBUCK, 256, 0, stream>>>(buck, bucket_cursor, cv, base, cnt);
    gemm_kernel<<<NB_GEMM, 256, 0, stream>>>(xb, Wt, pre);
    spmm_kernel<<<N_NODES / 4, 256, 0, stream>>>(pre, base, cnt, cv, out);
}